// Round 3
// baseline (74.435 us; speedup 1.0000x reference)
//
#include <hip/hip_runtime.h>

#define N_ 256
#define C_ 3
#define T_ 600
#define V_ 25
#define M_ 2
#define UPS 20                 // units per (n,c) slab
#define GPU_ 15                // row-pair groups per unit (300 / UPS)
#define NSLAB (N_ * C_)        // 768
#define NBLK (NSLAB * UPS / 8) // 1920 blocks (8 units of 32 lanes per 256-thr block)

__global__ void zero_ws_kernel(float* __restrict__ ws, int n) {
    int i = blockIdx.x * blockDim.x + threadIdx.x;
    if (i < n) ws[i] = 0.0f;
}

// Unit = 25 active lanes of a 32-lane half-wave. Each unit owns 15 consecutive
// row-pair groups (2 t-rows = 100 floats = 25 aligned float4) of one (n,c) slab.
// Lane p loads float4 q=[4p,4p+4). Element->joint map (static per lane):
//   elems 0,1 -> bin vA(p), elems 2,3 -> bin vB(p); vA and vB each cover all 25
//   joints bijectively across p=0..24.
// Within-pair motion (row 2g -> 2g+1): x[q+50] fetched via 4 shuffles
// (lane p+12 .z/.w, lane p+13 .x/.y). Cross-pair motion (2g+1 -> 2g+2): carried
// shuffled register vs next iteration's load. Seam row-pair handled by one
// extra x-load at the end of the unit's range.
__global__ __launch_bounds__(256) void slab_kernel(const float* __restrict__ x,
                                                   const float* __restrict__ y,
                                                   float* __restrict__ absws,
                                                   float* __restrict__ sqws) {
    const int unit = blockIdx.x * 8 + (threadIdx.x >> 5);
    const int p    = threadIdx.x & 31;
    if (p >= 25) return;

    const int slab = unit / UPS;
    const int g0   = (unit % UPS) * GPU_;
    const int n    = slab / C_;

    const int lane = threadIdx.x & 63;
    const int s1 = lane + 12;   // exceeds 63 only for lanes whose result is unused
    const int s2 = lane + 13;

    const float4* __restrict__ xs = reinterpret_cast<const float4*>(x) + (size_t)slab * 7500 + p;
    const float4* __restrict__ ys = reinterpret_cast<const float4*>(y) + (size_t)slab * 7500 + p;

    const bool m01 = (p <= 12);   // elems 0,1 are row-0 (q<50) iff p<=12
    const bool m23 = (p <= 11);   // elems 2,3 are row-0 iff p<=11

    float sqA = 0.f, sqB = 0.f, mA = 0.f, mB = 0.f;

    auto process = [&](const float4 x4, const float4 y4, bool do_odd,
                       const float4 xprev) -> float4 {
        float e0 = x4.x - y4.x, e1 = x4.y - y4.y;
        float e2 = x4.z - y4.z, e3 = x4.w - y4.w;
        sqA += e0 * e0 + e1 * e1;
        sqB += e2 * e2 + e3 * e3;
        float4 sh;
        sh.x = __shfl(x4.z, s1);
        sh.y = __shfl(x4.w, s1);
        sh.z = __shfl(x4.x, s2);
        sh.w = __shfl(x4.y, s2);
        float c01 = fabsf(sh.x - x4.x) + fabsf(sh.y - x4.y);
        float c23 = fabsf(sh.z - x4.z) + fabsf(sh.w - x4.w);
        if (do_odd) {
            c01 += fabsf(x4.x - xprev.x) + fabsf(x4.y - xprev.y);
            c23 += fabsf(x4.z - xprev.z) + fabsf(x4.w - xprev.w);
        }
        mA += m01 ? c01 : 0.f;
        mB += m23 ? c23 : 0.f;
        return sh;
    };

    // prologue: first group, no cross-pair term (previous unit's seam covers it)
    float4 xa = xs[(size_t)g0 * 25];
    float4 ya = ys[(size_t)g0 * 25];
    float4 xshp = process(xa, ya, false, xa);

    #pragma unroll 2
    for (int i = 1; i < GPU_; i += 2) {
        float4 x1 = xs[(size_t)(g0 + i) * 25];
        float4 y1 = ys[(size_t)(g0 + i) * 25];
        float4 x2 = xs[(size_t)(g0 + i + 1) * 25];
        float4 y2 = ys[(size_t)(g0 + i + 1) * 25];
        float4 sh1 = process(x1, y1, true, xshp);
        xshp = process(x2, y2, true, sh1);
    }

    // seam: cross-pair (last row of range -> first row of next group)
    if (g0 + GPU_ < 300) {
        float4 xn = xs[(size_t)(g0 + GPU_) * 25];
        float o01 = fabsf(xn.x - xshp.x) + fabsf(xn.y - xshp.y);
        float o23 = fabsf(xn.z - xshp.z) + fabsf(xn.w - xshp.w);
        mA += m01 ? o01 : 0.f;
        mB += m23 ? o23 : 0.f;
    }

    const int vA = (p < 12) ? 2 * p     : (p == 12 ? 24 : 2 * p - 25);
    const int vB = (p < 12) ? 2 * p + 1 : (p == 12 ? 0  : 2 * p - 24);
    atomicAdd(&absws[n * V_ + vA], mA);
    atomicAdd(&absws[n * V_ + vB], mB);
    atomicAdd(&sqws[n * V_ + vA], sqA);
    atomicAdd(&sqws[n * V_ + vB], sqB);
}

// final = (1/TOT) * sum_n sum_v (V * abs[n,v] / sum_v abs[n,.]) * sq[n,v]
__global__ __launch_bounds__(256) void finalize_kernel(const float* __restrict__ absws,
                                                       const float* __restrict__ sqws,
                                                       float* __restrict__ out) {
    const int n = threadIdx.x;                      // 256 threads = 256 samples
    float sumAbs = 0.0f;
    #pragma unroll
    for (int v = 0; v < V_; ++v) sumAbs += absws[n * V_ + v];
    float sumW = 0.0f;
    #pragma unroll
    for (int v = 0; v < V_; ++v) sumW += absws[n * V_ + v] * sqws[n * V_ + v];
    float partial = (float)V_ * sumW / sumAbs;

    __shared__ float red[256];
    red[n] = partial;
    __syncthreads();
    for (int s = 128; s > 0; s >>= 1) {
        if (n < s) red[n] += red[n + s];
        __syncthreads();
    }
    if (n == 0) out[0] = red[0] / (float)((size_t)N_ * C_ * T_ * V_ * M_);
}

extern "C" void kernel_launch(void* const* d_in, const int* in_sizes, int n_in,
                              void* d_out, int out_size, void* d_ws, size_t ws_size,
                              hipStream_t stream) {
    const float* x = (const float*)d_in[0];
    const float* y = (const float*)d_in[1];
    float* out   = (float*)d_out;
    float* absws = (float*)d_ws;            // N*V floats
    float* sqws  = absws + N_ * V_;         // N*V floats

    const int nws = 2 * N_ * V_;            // 12800 floats
    zero_ws_kernel<<<(nws + 255) / 256, 256, 0, stream>>>(absws, nws);

    slab_kernel<<<NBLK, 256, 0, stream>>>(x, y, absws, sqws);

    finalize_kernel<<<1, 256, 0, stream>>>(absws, sqws, out);
}

// Round 4
// 42.962 us; speedup vs baseline: 1.7326x; 1.7326x over previous
//
#include <hip/hip_runtime.h>

#define N_ 256
#define C_ 3
#define T_ 600
#define V_ 25
#define TG 60                    // row-pairs per tile (120 t-rows)
#define TILES_PER_SLAB 5         // 300 row-pairs / TG
#define NBLK (N_ * C_ * TILES_PER_SLAB)   // 3840 blocks

// Tile kernel. Block = 256 threads (250 active for load/motion).
// Load phase: thread t -> (g = t/25, p = t%25). Pass k handles row-pair
// rp = k*10 + g; lane loads float4 #p of the 25 float4 making up that
// 100-float row-pair. Wave-level: 64 consecutive float4 = 1024 B contiguous.
// sq(x-y) accumulates into two STATIC joint bins per lane:
//   elems 0,1 -> vA(p), elems 2,3 -> vB(p)  (bijective over p=0..24).
// x is also staged linearly into LDS (row-pair rp at floats [rp*100, rp*100+100)).
// Motion phase: thread owns joint v = t%25, chunk c = t/25; reads float2
// (both m) columns from LDS at stride 50 floats, 12 temporal diffs per thread.
// Tile covers diffs r in [2*G0-1, 2*G0+118]; row 2*G0-1 staged from global
// into bnd[] (G0>0). Partition over the slab's 599 diffs is exact & disjoint.
__global__ __launch_bounds__(256, 4) void slab_kernel(const float* __restrict__ x,
                                                      const float* __restrict__ y,
                                                      float* __restrict__ absws,
                                                      float* __restrict__ sqws) {
    __shared__ float xt[TG * 100];   // 24000 B: x tile, rows [2G0, 2G0+120)
    __shared__ float bnd[50];        // row 2G0-1
    __shared__ float binAbs[32], binSq[32];

    const int t    = threadIdx.x;
    const int bid  = blockIdx.x;
    const int slab = bid / TILES_PER_SLAB;   // n*3 + c
    const int tile = bid % TILES_PER_SLAB;
    const int G0   = tile * TG;
    const int n    = slab / C_;

    if (t < 32) { binAbs[t] = 0.f; binSq[t] = 0.f; }

    const bool active = (t < 250);
    const int p = t % 25;
    const int g = t / 25;                    // 0..9

    const float4* __restrict__ xs4 = reinterpret_cast<const float4*>(x) + (size_t)slab * 7500 + (size_t)G0 * 25;
    const float4* __restrict__ ys4 = reinterpret_cast<const float4*>(y) + (size_t)slab * 7500 + (size_t)G0 * 25;

    float sqA = 0.f, sqB = 0.f;

    if (active) {
        #pragma unroll
        for (int h = 0; h < 2; ++h) {        // two batches of 3 passes: 6 loads in flight
            float4 xv[3], yv[3];
            #pragma unroll
            for (int k = 0; k < 3; ++k) {
                const int rp = (h * 3 + k) * 10 + g;
                xv[k] = xs4[rp * 25 + p];
                yv[k] = ys4[rp * 25 + p];
            }
            #pragma unroll
            for (int k = 0; k < 3; ++k) {
                const int rp = (h * 3 + k) * 10 + g;
                *reinterpret_cast<float4*>(&xt[rp * 100 + 4 * p]) = xv[k];
                const float e0 = xv[k].x - yv[k].x, e1 = xv[k].y - yv[k].y;
                const float e2 = xv[k].z - yv[k].z, e3 = xv[k].w - yv[k].w;
                sqA += e0 * e0 + e1 * e1;
                sqB += e2 * e2 + e3 * e3;
            }
        }
    }
    if (G0 > 0 && t < 25) {                  // stage boundary row 2G0-1 (8B-aligned)
        const float2* b2 = reinterpret_cast<const float2*>(x) + (size_t)slab * 15000 + (size_t)(2 * G0 - 1) * 25;
        reinterpret_cast<float2*>(bnd)[t] = b2[t];
    }
    __syncthreads();

    if (active) {
        const int v = p;                     // motion joint (static per thread)
        const int c = g;                     // chunk of 12 diffs
        int j0 = 12 * c;
        const int j1 = j0 + 12;
        const float2* rows = reinterpret_cast<const float2*>(xt);
        float2 prev;
        if (j0 == 0) {
            if (G0 > 0) prev = reinterpret_cast<const float2*>(bnd)[v];
            else { prev = rows[v]; j0 = 1; } // slab start: no diff r=-1
        } else {
            prev = rows[(j0 - 1) * 25 + v];
        }
        float mot = 0.f;
        #pragma unroll
        for (int j = j0; j < j1; ++j) {
            const float2 cur = rows[j * 25 + v];
            mot += fabsf(cur.x - prev.x) + fabsf(cur.y - prev.y);
            prev = cur;
        }
        atomicAdd(&binAbs[v], mot);
        const int vA = (p < 12) ? 2 * p     : (p == 12 ? 24 : 2 * p - 25);
        const int vB = (p < 12) ? 2 * p + 1 : (p == 12 ? 0  : 2 * p - 24);
        atomicAdd(&binSq[vA], sqA);
        atomicAdd(&binSq[vB], sqB);
    }
    __syncthreads();

    if (t < V_) {
        atomicAdd(&absws[n * V_ + t], binAbs[t]);
        atomicAdd(&sqws[n * V_ + t], binSq[t]);
    }
}

// final = (1/TOT) * sum_n sum_v (V * abs[n,v] / sum_v abs[n,.]) * sq[n,v]
__global__ __launch_bounds__(256) void finalize_kernel(const float* __restrict__ absws,
                                                       const float* __restrict__ sqws,
                                                       float* __restrict__ out) {
    const int n = threadIdx.x;               // 256 threads = 256 samples
    float sumAbs = 0.0f;
    #pragma unroll
    for (int v = 0; v < V_; ++v) sumAbs += absws[n * V_ + v];
    float sumW = 0.0f;
    #pragma unroll
    for (int v = 0; v < V_; ++v) sumW += absws[n * V_ + v] * sqws[n * V_ + v];
    float partial = (float)V_ * sumW / sumAbs;

    __shared__ float red[256];
    red[n] = partial;
    __syncthreads();
    for (int s = 128; s > 0; s >>= 1) {
        if (n < s) red[n] += red[n + s];
        __syncthreads();
    }
    if (n == 0) out[0] = red[0] / (float)((size_t)N_ * C_ * T_ * 25 * 2);
}

extern "C" void kernel_launch(void* const* d_in, const int* in_sizes, int n_in,
                              void* d_out, int out_size, void* d_ws, size_t ws_size,
                              hipStream_t stream) {
    const float* x = (const float*)d_in[0];
    const float* y = (const float*)d_in[1];
    float* out   = (float*)d_out;
    float* absws = (float*)d_ws;             // N*V floats
    float* sqws  = absws + N_ * V_;          // N*V floats

    hipMemsetAsync(d_ws, 0, (size_t)(2 * N_ * V_) * sizeof(float), stream);

    slab_kernel<<<NBLK, 256, 0, stream>>>(x, y, absws, sqws);

    finalize_kernel<<<1, 256, 0, stream>>>(absws, sqws, out);
}